// Round 22
// baseline (134.217 us; speedup 1.0000x reference)
//
#include <hip/hip_runtime.h>
#include <hip/hip_fp16.h>

#define T_DIM 7
#define H_DIM 96
#define W_DIM 96
#define HW    (H_DIM*W_DIM)          // 9216
#define L_DIM (T_DIM*HW)             // 64512
#define NTAPS 27

// tile: 8 rows x 16 cols = 128 locs/block; 512 thr = 8 waves = 4 pairs x 2
// K-halves. Pair p owns rows {2p,2p+1}; each wave gathers/computes its own
// 32-channel K-half (checkless, zero-padded halo); halves reduced at phase end.
#define TR 8
#define TC 16
#define HR (TR+8)                    // 16 halo rows
#define HC (TC+8)                    // 24 halo cols
#define HROWB (HC*128)               // 3072 B per halo row
#define HALO_B (HR*HROWB)            // 49152
#define WBUF_OFF HALO_B              // 2 x 8KB weight double-buffer
#define SOFF_OFF (HALO_B + 16384)    // 65536
#define SOFF_STRIDE 108              // 27 dwords per loc
#define SMEM_B (SOFF_OFF + 128*SOFF_STRIDE)   // 79360 -> 2 blocks/CU

typedef __attribute__((ext_vector_type(8))) _Float16 f16x8;
typedef __attribute__((ext_vector_type(4))) float f32x4;

#define GLOAD16(gp, lp) \
    __builtin_amdgcn_global_load_lds((const __attribute__((address_space(1))) unsigned int*)(gp), \
                                     (__attribute__((address_space(3))) unsigned int*)(lp), 16, 0, 0)

// ---------------------------------------------------------------------------
// zfill: 4KB of zeros (guard buffer for zero-padded halo staging)
// ---------------------------------------------------------------------------
__global__ void zfill(int4* __restrict__ z)
{
    z[threadIdx.x] = make_int4(0, 0, 0, 0);
}

// ---------------------------------------------------------------------------
// prep_weights: [O][C][27] fp32 -> [27][O(64-pad)][C] f16, 16B slot rotated by
// o (R13-proven: 2-way LDS B-reads, staged linearly by gload_lds).
// ---------------------------------------------------------------------------
__global__ void prep_weights(const float* __restrict__ woff0,
                             const float* __restrict__ w0,
                             const float* __restrict__ woff1,
                             const float* __restrict__ w1,
                             unsigned short* __restrict__ dst)
{
    int idx = blockIdx.x * 256 + threadIdx.x;
    const int per = NTAPS * 64 * 64;           // 110592
    if (idx >= 4 * per) return;
    int which = idx / per;
    int r     = idx % per;
    int tap   = r / 4096;
    int o     = (r >> 6) & 63;
    int c     = r & 63;
    const float* src = (which == 0) ? woff0 : (which == 1) ? w0
                     : (which == 2) ? woff1 : w1;
    int omax = (which == 0 || which == 2) ? 54 : 64;
    float v = 0.f;
    if (o < omax) v = src[(o * 64 + c) * NTAPS + tap];
    __half h = __float2half(v);
    int slot = (((c >> 3) + o) & 7);
    int pos  = tap * 4096 + o * 64 + slot * 8 + (c & 7);
    dst[which * per + pos] = __half_as_ushort(h);
}

// ---------------------------------------------------------------------------
// transpose_x: x [C=64][L] fp32 -> xt [L][64] f16 (linear, packed dwords)
// ---------------------------------------------------------------------------
__global__ void transpose_x(const float* __restrict__ x, unsigned* __restrict__ xt2)
{
    __shared__ float tile[64][65];
    const int tid = threadIdx.x;
    const int lb  = blockIdx.x * 64;
    const int ln  = tid & 63;
    const int q   = tid >> 6;    // 0..3
#pragma unroll
    for (int i = 0; i < 16; ++i) {
        int c = q + 4 * i;
        tile[ln][c] = x[(size_t)c * L_DIM + lb + ln];
    }
    __syncthreads();
    const int ln2 = tid & 31, q2 = tid >> 5;   // 0..7
#pragma unroll
    for (int i = 0; i < 8; ++i) {
        int ll = q2 + 8 * i;
        __half2 h2 = __float22half2_rn(make_float2(tile[ll][2*ln2], tile[ll][2*ln2+1]));
        xt2[(size_t)(lb + ll) * 32 + ln2] = *reinterpret_cast<unsigned*>(&h2);
    }
}

// ---- stage halo slab for kt (48KB), SOURCE-pre-swizzled + ZERO-PADDED ------
// ROW+COL-keyed: chunk (sl-hc-hr)&7 lives at slot sl of cell (hr,hc); readers
// use slot (ck+hc+hr)&7 -> same-col/diff-row lanes now hit different banks.
#define STAGE_SLAB(KT) { \
    int tp_ = t + (KT) - 1; \
    bool tvz_ = (tp_ >= 0) && (tp_ < T_DIM); \
    const unsigned char* sb_ = xb + (size_t)(tvz_ ? tp_ : 0) * HW * 128; \
    _Pragma("unroll") \
    for (int i = 0; i < 6; ++i) { \
        int p16_ = tid + i * 512; \
        int hr_ = p16_ / 192; \
        int rem_ = p16_ - hr_ * 192; \
        int hc_ = rem_ >> 3; \
        int sl_ = rem_ & 7; \
        int ch_ = (sl_ - hc_ - hr_) & 7; \
        int gr_ = row0 - 4 + hr_; \
        int gc_ = col0 - 4 + hc_; \
        bool ok_ = tvz_ && (gr_ >= 0) && (gr_ < H_DIM) && (gc_ >= 0) && (gc_ < W_DIM); \
        const unsigned char* src_ = ok_ \
            ? (sb_ + (size_t)(gr_ * W_DIM + gc_) * 128 + ch_ * 16) \
            : (zb + sl_ * 16); \
        GLOAD16(src_, smem + (i << 13) + (wv << 10)); \
    } }

// stage weight tap K into buf[K&1] (8KB, 1 gload/thread at 512 threads)
#define WSTAGE(WG, K) \
    GLOAD16((WG) + (size_t)(K) * 8192 + tid * 16, \
            smem + WBUF_OFF + (((K) & 1) << 13) + (wv << 10));

#define READ_OFF(MT, K) ({ \
    unsigned u_ = *(const unsigned*)(smem + SOFF_OFF + \
        ((2 * pair + (MT)) * 16 + lr) * SOFF_STRIDE + (K) * 4); \
    __half22float2(*reinterpret_cast<__half2*>(&u_)); })

// K-split deform gather for row-tile MT (checkless; my 32-ch half = chunk ck)
#define GATHER_D(MT, O2, AV) { \
    float ph_ = (float)(row0 + 2 * pair + (MT) + kh - 1) + (O2).x; \
    float pw_ = (float)(col0 + lr + kw - 1) + (O2).y; \
    float hf_ = floorf(ph_), wf_ = floorf(pw_); \
    float lh_ = ph_ - hf_, lw_ = pw_ - wf_; \
    int sr_ = min(max((int)hf_ - row0 + 4, 0), HR - 2); \
    int sc_ = min(max((int)wf_ - col0 + 4, 0), HC - 2); \
    __half2 cw00_ = __float2half2_rn((1.f - lh_) * (1.f - lw_)); \
    __half2 cw01_ = __float2half2_rn((1.f - lh_) * lw_); \
    __half2 cw10_ = __float2half2_rn(lh_ * (1.f - lw_)); \
    __half2 cw11_ = __float2half2_rn(lh_ * lw_); \
    const unsigned char* r0_ = smem + sr_ * HROWB; \
    const unsigned char* r1_ = r0_ + HROWB; \
    int base_ = ck + sc_ + sr_; \
    int c00_ = sc_ * 128 + ((base_ & 7) << 4); \
    int c01_ = (sc_ + 1) * 128 + (((base_ + 1) & 7) << 4); \
    int c10_ = sc_ * 128 + (((base_ + 1) & 7) << 4); \
    int c11_ = (sc_ + 1) * 128 + (((base_ + 2) & 7) << 4); \
    f16x8 v00_ = *(const f16x8*)(r0_ + c00_), v01_ = *(const f16x8*)(r0_ + c01_); \
    f16x8 v10_ = *(const f16x8*)(r1_ + c10_), v11_ = *(const f16x8*)(r1_ + c11_); \
    const __half2* p00_ = (const __half2*)&v00_; \
    const __half2* p01_ = (const __half2*)&v01_; \
    const __half2* p10_ = (const __half2*)&v10_; \
    const __half2* p11_ = (const __half2*)&v11_; \
    __align__(16) __half2 va_[4]; \
    _Pragma("unroll") \
    for (int d = 0; d < 4; ++d) { \
        __half2 s_ = __hmul2(p00_[d], cw00_); \
        s_ = __hfma2(p01_[d], cw01_, s_); \
        s_ = __hfma2(p10_[d], cw10_, s_); \
        s_ = __hfma2(p11_[d], cw11_, s_); \
        va_[d] = s_; \
    } \
    AV = *reinterpret_cast<f16x8*>(&va_[0]); }

// K-split integer-shift gather for row-tile MT (checkless)
#define GATHER_C(MT, AV) { \
    int sr_ = 2 * pair + (MT) + kh + 3, sc_ = lr + kw + 3; \
    int4 z_ = *(const int4*)(smem + sr_ * HROWB + sc_ * 128 + \
                             (((ck + sc_ + sr_) & 7) << 4)); \
    AV = *reinterpret_cast<f16x8*>(&z_); }

#define MFMA_F16(A, B, C) __builtin_amdgcn_mfma_f32_16x16x32_f16( \
    A, *reinterpret_cast<f16x8*>(&(B)), C, 0, 0, 0)

// one conv phase (27 taps): gathers + B from LDS, K-split.
// Sync: counted vmcnt only (gload_lds -> B-read ordering); NO lgkm drains —
// every ds_read is consumed by lerp/MFMA before the barrier in program order.
#define RUN_PHASE(DEF, WGBLP) { \
    const unsigned char* wgbl_ = (WGBLP); \
    __builtin_amdgcn_s_barrier(); \
    STAGE_SLAB(0); \
    WSTAGE(wgbl_, 0); \
    float2 oc0, oc1, on0, on1; \
    oc0 = make_float2(0.f, 0.f); oc1 = oc0; on0 = oc0; on1 = oc0; \
    if (DEF) { oc0 = READ_OFF(0, 0); oc1 = READ_OFF(1, 0); } \
    asm volatile("s_waitcnt vmcnt(0)" ::: "memory"); \
    __builtin_amdgcn_s_barrier(); \
    __builtin_amdgcn_sched_barrier(0); \
    _Pragma("unroll 1") \
    for (int kt = 0; kt < 3; ++kt) { \
        if (kt > 0) { \
            __builtin_amdgcn_s_barrier(); \
            STAGE_SLAB(kt); \
            asm volatile("s_waitcnt vmcnt(0)" ::: "memory"); \
            __builtin_amdgcn_s_barrier(); \
            __builtin_amdgcn_sched_barrier(0); \
        } \
        _Pragma("unroll 1") \
        for (int k9 = 0; k9 < 9; ++k9) { \
            int k = kt * 9 + k9; \
            if (k > 0) { \
                asm volatile("s_waitcnt vmcnt(0)" ::: "memory"); \
                __builtin_amdgcn_s_barrier(); \
                __builtin_amdgcn_sched_barrier(0); \
            } \
            if (k + 1 < NTAPS) { \
                WSTAGE(wgbl_, k + 1); \
                if (DEF) { on0 = READ_OFF(0, k + 1); on1 = READ_OFF(1, k + 1); } \
            } \
            int kh = k9 / 3, kw = k9 - (k9 / 3) * 3; \
            f16x8 a0, a1; \
            if (DEF) { GATHER_D(0, oc0, a0); GATHER_D(1, oc1, a1); } \
            else     { GATHER_C(0, a0);      GATHER_C(1, a1); } \
            const unsigned char* br_ = smem + WBUF_OFF + ((k & 1) << 13) + lr * 128; \
            _Pragma("unroll") \
            for (int n = 0; n < 4; ++n) { \
                f16x8 b_ = *(const f16x8*)(br_ + n * 2048 + sb); \
                acc[0][n] = MFMA_F16(a0, b_, acc[0][n]); \
                acc[1][n] = MFMA_F16(a1, b_, acc[1][n]); \
            } \
            oc0 = on0; oc1 = on1; \
        } \
    } }

// cross-K-half reduce: kh2==1 stores, kh2==0 adds (halo region is dead here)
#define REDUCE_KSPLIT() { \
    __syncthreads(); \
    if (kh2 == 1) { \
        _Pragma("unroll") \
        for (int mt = 0; mt < 2; ++mt) \
            _Pragma("unroll") \
            for (int n = 0; n < 4; ++n) \
                *(f32x4*)(smem + pair * 8192 + ((mt * 4 + n) << 10) + (lane << 4)) = acc[mt][n]; \
    } \
    __syncthreads(); \
    if (kh2 == 0) { \
        _Pragma("unroll") \
        for (int mt = 0; mt < 2; ++mt) \
            _Pragma("unroll") \
            for (int n = 0; n < 4; ++n) { \
                f32x4 o_ = *(const f32x4*)(smem + pair * 8192 + ((mt * 4 + n) << 10) + (lane << 4)); \
                acc[mt][n] += o_; \
            } \
    } }

// ---------------------------------------------------------------------------
// dcn_ks4: fused (offset conv + deform conv); 512 thr K-split waves, zero-
// padded checkless halo gathers (row+col swizzle), B in LDS, minimal sync.
//   EPI 1: +bias+leaky -> f16 [loc][64].  EPI 2: +bias+residual -> f32 NCDHW.
// ---------------------------------------------------------------------------
template<int EPI>
__global__ __launch_bounds__(512, 2)
void dcn_ks4(const unsigned short* __restrict__ xin,   // f16 [L][64]
             const unsigned short* __restrict__ Wtoff, // f16 [27][64][64] swz
             const unsigned short* __restrict__ Wtm,   // f16 [27][64][64] swz
             const float* __restrict__ boff,           // [54]
             const float* __restrict__ bmain,          // [64]
             const float* __restrict__ resid,          // f32 NCDHW (EPI==2)
             const unsigned char* __restrict__ zb,     // 4KB zeros
             float* __restrict__ outf,
             unsigned short* __restrict__ outh)
{
    __shared__ __align__(16) unsigned char smem[SMEM_B];

    const int tid  = threadIdx.x;
    const int wv   = tid >> 6, lane = tid & 63;
    const int lr   = lane & 15, lk = lane >> 4;
    const int pair = wv >> 1;          // 0..3 (rows 2p,2p+1)
    const int kh2  = wv & 1;           // K-half
    const int ck   = kh2 * 4 + lk;     // my 16B channel-chunk index (0..7)

    // XCD-contiguous swizzle: 504 = 8 x 63 (bijective)
    const int bid = blockIdx.x;
    const int wg  = (bid & 7) * 63 + (bid >> 3);
    const int t   = wg / 72;
    const int rg  = (wg % 72) / 6;
    const int cg  = wg % 6;
    const int row0 = rg * TR;
    const int col0 = cg * TC;

    const unsigned char* xb = (const unsigned char*)xin;

    // B-read slot (2-way, free): row o=n*16+lr, chunk ck
    const int sb = ((ck + lr) & 7) << 4;

    f32x4 acc[2][4];
#pragma unroll
    for (int mt = 0; mt < 2; ++mt)
#pragma unroll
        for (int n = 0; n < 4; ++n) acc[mt][n] = (f32x4){0.f, 0.f, 0.f, 0.f};

    // ================ PHASE A: offset conv -> soff LDS ================
    RUN_PHASE(false, (const unsigned char*)Wtoff);
    REDUCE_KSPLIT();
    if (kh2 == 0) {
#pragma unroll
        for (int n = 0; n < 4; ++n) {
            int o = n * 16 + lr;
            if (o < 54) {
                float bvA = boff[o];
#pragma unroll
                for (int mt = 0; mt < 2; ++mt)
#pragma unroll
                    for (int i = 0; i < 4; ++i) {
                        int l = (2 * pair + mt) * 16 + lk * 4 + i;
                        float vv = acc[mt][n][i] + bvA;
                        *(unsigned short*)(smem + SOFF_OFF + l * SOFF_STRIDE + o * 2) =
                            __half_as_ushort(__float2half(vv));
                    }
            }
        }
    }
    __syncthreads();   // offsets visible (full drain, once per phase)

    // ================ PHASE B: deformable conv ================
#pragma unroll
    for (int mt = 0; mt < 2; ++mt)
#pragma unroll
        for (int n = 0; n < 4; ++n) acc[mt][n] = (f32x4){0.f, 0.f, 0.f, 0.f};

    RUN_PHASE(true, (const unsigned char*)Wtm);
    REDUCE_KSPLIT();
    if (kh2 == 1) return;

    float bv[4];
#pragma unroll
    for (int n = 0; n < 4; ++n) bv[n] = bmain[n * 16 + lr];

    if (EPI == 1) {
#pragma unroll
        for (int mt = 0; mt < 2; ++mt) {
            size_t lrowmt = (size_t)t * HW + (size_t)(row0 + 2 * pair + mt) * W_DIM + col0;
#pragma unroll
            for (int n = 0; n < 4; ++n)
#pragma unroll
                for (int i = 0; i < 4; ++i) {
                    int lc = lk * 4 + i;
                    float vv = acc[mt][n][i] + bv[n];
                    vv = (vv > 0.f) ? vv : 0.1f * vv;
                    outh[(lrowmt + lc) * 64 + n * 16 + lr] =
                        __half_as_ushort(__float2half(vv));
                }
        }
    } else {
        // transpose via pair-private 8KB LDS (halo dead; reduce consumed)
        float* tf = (float*)(smem + pair * 8192);
#pragma unroll
        for (int mt = 0; mt < 2; ++mt)
#pragma unroll
            for (int n = 0; n < 4; ++n)
#pragma unroll
                for (int i = 0; i < 4; ++i) {
                    int l = mt * 16 + lk * 4 + i;
                    int och = n * 16 + lr;
                    tf[l * 64 + ((och + 2 * l) & 63)] = acc[mt][n][i] + bv[n];
                }
        asm volatile("s_waitcnt lgkmcnt(0)" ::: "memory");
        __builtin_amdgcn_sched_barrier(0);
        int j = lane & 15, gq = lane >> 4;
#pragma unroll
        for (int mt = 0; mt < 2; ++mt) {
            size_t lrowmt = (size_t)t * HW + (size_t)(row0 + 2 * pair + mt) * W_DIM + col0;
#pragma unroll
            for (int it = 0; it < 16; ++it) {
                int och = gq * 16 + it;
                int l = mt * 16 + j;
                float val = tf[l * 64 + ((och + 2 * l) & 63)];
                size_t gi = (size_t)och * L_DIM + lrowmt + j;
                outf[gi] = val + resid[gi];
            }
        }
    }
}

// ---------------------------------------------------------------------------
extern "C" void kernel_launch(void* const* d_in, const int* in_sizes, int n_in,
                              void* d_out, int out_size, void* d_ws, size_t ws_size,
                              hipStream_t stream)
{
    const float* x     = (const float*)d_in[0];
    const float* woff0 = (const float*)d_in[1];
    const float* boff0 = (const float*)d_in[2];
    const float* w0    = (const float*)d_in[3];
    const float* b0    = (const float*)d_in[4];
    const float* woff1 = (const float*)d_in[5];
    const float* boff1 = (const float*)d_in[6];
    const float* w1    = (const float*)d_in[7];
    const float* b1    = (const float*)d_in[8];
    float* out = (float*)d_out;

    unsigned char* ws = (unsigned char*)d_ws;
    unsigned short* Wt  = (unsigned short*)ws;                  // 884736 B (4x f16 [27][64][64] swz)
    unsigned short* xt  = (unsigned short*)(ws + 884736);       // 8257536 B f16 [L][64]
    unsigned short* y   = (unsigned short*)(ws + 9142272);      // 8257536 B f16 [L][64]
    unsigned char*  zb  = ws + 17399808;                        // 4096 B zeros

    zfill<<<1, 256, 0, stream>>>((int4*)zb);
    prep_weights<<<1728, 256, 0, stream>>>(woff0, w0, woff1, w1, Wt);
    transpose_x<<<1008, 256, 0, stream>>>(x, (unsigned*)xt);

    const int grid = T_DIM * (H_DIM / TR) * (W_DIM / TC);   // 504 x 512 threads
    const int WSZ  = NTAPS * 64 * 64;                       // 110592

    // layer 0 (fused offset-conv + deform + leaky) : xt -> y
    dcn_ks4<1><<<grid, 512, 0, stream>>>(xt, Wt,           Wt + WSZ,     boff0, b0, nullptr, zb, nullptr, y);
    // layer 1 (fused offset-conv + deform + residual) : y -> out
    dcn_ks4<2><<<grid, 512, 0, stream>>>(y,  Wt + 2 * WSZ, Wt + 3 * WSZ, boff1, b1, x,       zb, out, nullptr);
}

// Round 23
// 128.541 us; speedup vs baseline: 1.0442x; 1.0442x over previous
//
#include <hip/hip_runtime.h>
#include <hip/hip_fp16.h>

#define T_DIM 7
#define H_DIM 96
#define W_DIM 96
#define HW    (H_DIM*W_DIM)          // 9216
#define L_DIM (T_DIM*HW)             // 64512
#define NTAPS 27

// tile: 8 rows x 16 cols = 128 locs/block; 4 waves, wave = rows {2wv, 2wv+1},
// full K=64 per wave; B-frags shared across the 2 row-tiles (R16-proven).
#define TR 8
#define TC 16
#define HR (TR+8)                    // 16 halo rows
#define HC (TC+8)                    // 24 halo cols
#define HROWB (HC*128)               // 3072 B per halo row
#define HALO_B (HR*HROWB)            // 49152
#define WBUF_OFF HALO_B              // 2 x 8KB weight double-buffer
#define SOFF_OFF (HALO_B + 16384)    // 65536
#define SOFF_STRIDE 108              // 27 dwords per loc
#define SMEM_B (SOFF_OFF + 128*SOFF_STRIDE)   // 79360 -> 2 blocks/CU

typedef __attribute__((ext_vector_type(8))) _Float16 f16x8;
typedef __attribute__((ext_vector_type(4))) float f32x4;

#define GLOAD16(gp, lp) \
    __builtin_amdgcn_global_load_lds((const __attribute__((address_space(1))) unsigned int*)(gp), \
                                     (__attribute__((address_space(3))) unsigned int*)(lp), 16, 0, 0)

// ---------------------------------------------------------------------------
// zfill: 4KB of zeros (guard buffer for zero-padded halo staging)
// ---------------------------------------------------------------------------
__global__ void zfill(int4* __restrict__ z)
{
    z[threadIdx.x] = make_int4(0, 0, 0, 0);
}

// ---------------------------------------------------------------------------
// prep_weights: [O][C][27] fp32 -> [27][O(64-pad)][C] f16, 16B slot rotated by
// o (R13-proven: 2-way LDS B-reads, staged linearly by gload_lds).
// ---------------------------------------------------------------------------
__global__ void prep_weights(const float* __restrict__ woff0,
                             const float* __restrict__ w0,
                             const float* __restrict__ woff1,
                             const float* __restrict__ w1,
                             unsigned short* __restrict__ dst)
{
    int idx = blockIdx.x * 256 + threadIdx.x;
    const int per = NTAPS * 64 * 64;           // 110592
    if (idx >= 4 * per) return;
    int which = idx / per;
    int r     = idx % per;
    int tap   = r / 4096;
    int o     = (r >> 6) & 63;
    int c     = r & 63;
    const float* src = (which == 0) ? woff0 : (which == 1) ? w0
                     : (which == 2) ? woff1 : w1;
    int omax = (which == 0 || which == 2) ? 54 : 64;
    float v = 0.f;
    if (o < omax) v = src[(o * 64 + c) * NTAPS + tap];
    __half h = __float2half(v);
    int slot = (((c >> 3) + o) & 7);
    int pos  = tap * 4096 + o * 64 + slot * 8 + (c & 7);
    dst[which * per + pos] = __half_as_ushort(h);
}

// ---------------------------------------------------------------------------
// transpose_x: x [C=64][L] fp32 -> xt [L][64] f16 (linear, packed dwords)
// ---------------------------------------------------------------------------
__global__ void transpose_x(const float* __restrict__ x, unsigned* __restrict__ xt2)
{
    __shared__ float tile[64][65];
    const int tid = threadIdx.x;
    const int lb  = blockIdx.x * 64;
    const int ln  = tid & 63;
    const int q   = tid >> 6;    // 0..3
#pragma unroll
    for (int i = 0; i < 16; ++i) {
        int c = q + 4 * i;
        tile[ln][c] = x[(size_t)c * L_DIM + lb + ln];
    }
    __syncthreads();
    const int ln2 = tid & 31, q2 = tid >> 5;   // 0..7
#pragma unroll
    for (int i = 0; i < 8; ++i) {
        int ll = q2 + 8 * i;
        __half2 h2 = __float22half2_rn(make_float2(tile[ll][2*ln2], tile[ll][2*ln2+1]));
        xt2[(size_t)(lb + ll) * 32 + ln2] = *reinterpret_cast<unsigned*>(&h2);
    }
}

// ---- stage halo slab for kt (48KB), SOURCE-pre-swizzled + ZERO-PADDED:
// out-of-image cells are staged from the zero guard buffer, so downstream
// gathers need no bounds checks (zero value x any weight = 0, = reference).
#define STAGE_SLAB(KT) { \
    int tp_ = t + (KT) - 1; \
    bool tvz_ = (tp_ >= 0) && (tp_ < T_DIM); \
    const unsigned char* sb_ = xb + (size_t)(tvz_ ? tp_ : 0) * HW * 128; \
    _Pragma("unroll") \
    for (int i = 0; i < 12; ++i) { \
        int p16_ = tid + i * 256; \
        int hr_ = p16_ / 192; \
        int rem_ = p16_ - hr_ * 192; \
        int hc_ = rem_ >> 3; \
        int sl_ = rem_ & 7; \
        int ch_ = (sl_ - hc_) & 7; \
        int gr_ = row0 - 4 + hr_; \
        int gc_ = col0 - 4 + hc_; \
        bool ok_ = tvz_ && (gr_ >= 0) && (gr_ < H_DIM) && (gc_ >= 0) && (gc_ < W_DIM); \
        const unsigned char* src_ = ok_ \
            ? (sb_ + (size_t)(gr_ * W_DIM + gc_) * 128 + ch_ * 16) \
            : (zb + sl_ * 16); \
        GLOAD16(src_, smem + (i << 12) + (wv << 10)); \
    } }

// stage weight tap K into buf[K&1] (8KB, 2 gloads/thread)
#define WSTAGE(WG, K) { \
    const unsigned char* ws_ = (WG) + (size_t)(K) * 8192 + tid * 16; \
    unsigned char* ld_ = smem + WBUF_OFF + (((K) & 1) << 13) + (wv << 10); \
    GLOAD16(ws_,        ld_); \
    GLOAD16(ws_ + 4096, ld_ + 4096); }

#define READ_OFF(MT, K) ({ \
    unsigned u_ = *(const unsigned*)(smem + SOFF_OFF + \
        ((2 * wv + (MT)) * 16 + lr) * SOFF_STRIDE + (K) * 4); \
    __half22float2(*reinterpret_cast<__half2*>(&u_)); })

// deform gather for row-tile MT (zero-padded halo: no per-corner checks)
#define GATHER_D(MT, O2, A0, A1) { \
    float ph_ = (float)(row0 + 2 * wv + (MT) + kh - 1) + (O2).x; \
    float pw_ = (float)(col0 + lr + kw - 1) + (O2).y; \
    float hf_ = floorf(ph_), wf_ = floorf(pw_); \
    float lh_ = ph_ - hf_, lw_ = pw_ - wf_; \
    int sr_ = min(max((int)hf_ - row0 + 4, 0), HR - 2); \
    int sc_ = min(max((int)wf_ - col0 + 4, 0), HC - 2); \
    __half2 cw00_ = __float2half2_rn((1.f - lh_) * (1.f - lw_)); \
    __half2 cw01_ = __float2half2_rn((1.f - lh_) * lw_); \
    __half2 cw10_ = __float2half2_rn(lh_ * (1.f - lw_)); \
    __half2 cw11_ = __float2half2_rn(lh_ * lw_); \
    const unsigned char* r0_ = smem + sr_ * HROWB; \
    const unsigned char* r1_ = r0_ + HROWB; \
    int c0a_ = sc_ * 128 + (((lk + sc_) & 7) << 4); \
    int c0b_ = sc_ * 128 + (((lk + 4 + sc_) & 7) << 4); \
    int c1a_ = (sc_ + 1) * 128 + (((lk + 1 + sc_) & 7) << 4); \
    int c1b_ = (sc_ + 1) * 128 + (((lk + 5 + sc_) & 7) << 4); \
    f16x8 v00a_ = *(const f16x8*)(r0_ + c0a_), v00b_ = *(const f16x8*)(r0_ + c0b_); \
    f16x8 v01a_ = *(const f16x8*)(r0_ + c1a_), v01b_ = *(const f16x8*)(r0_ + c1b_); \
    f16x8 v10a_ = *(const f16x8*)(r1_ + c0a_), v10b_ = *(const f16x8*)(r1_ + c0b_); \
    f16x8 v11a_ = *(const f16x8*)(r1_ + c1a_), v11b_ = *(const f16x8*)(r1_ + c1b_); \
    __align__(16) __half2 va_[8]; \
    const __half2* p00a_ = (const __half2*)&v00a_; \
    const __half2* p01a_ = (const __half2*)&v01a_; \
    const __half2* p10a_ = (const __half2*)&v10a_; \
    const __half2* p11a_ = (const __half2*)&v11a_; \
    const __half2* p00b_ = (const __half2*)&v00b_; \
    const __half2* p01b_ = (const __half2*)&v01b_; \
    const __half2* p10b_ = (const __half2*)&v10b_; \
    const __half2* p11b_ = (const __half2*)&v11b_; \
    _Pragma("unroll") \
    for (int d = 0; d < 4; ++d) { \
        __half2 s0_ = __hmul2(p00a_[d], cw00_); \
        s0_ = __hfma2(p01a_[d], cw01_, s0_); \
        s0_ = __hfma2(p10a_[d], cw10_, s0_); \
        s0_ = __hfma2(p11a_[d], cw11_, s0_); \
        va_[d] = s0_; \
        __half2 s1_ = __hmul2(p00b_[d], cw00_); \
        s1_ = __hfma2(p01b_[d], cw01_, s1_); \
        s1_ = __hfma2(p10b_[d], cw10_, s1_); \
        s1_ = __hfma2(p11b_[d], cw11_, s1_); \
        va_[4 + d] = s1_; \
    } \
    A0 = *reinterpret_cast<f16x8*>(&va_[0]); \
    A1 = *reinterpret_cast<f16x8*>(&va_[4]); }

// integer-shift gather for row-tile MT (zero-padded halo: no checks at all)
#define GATHER_C(MT, A0, A1) { \
    int sr_ = 2 * wv + (MT) + kh + 3, sc_ = lr + kw + 3; \
    const unsigned char* cell_ = smem + sr_ * HROWB + sc_ * 128; \
    int4 z0_ = *(const int4*)(cell_ + (((lk + sc_) & 7) << 4)); \
    int4 z1_ = *(const int4*)(cell_ + (((lk + 4 + sc_) & 7) << 4)); \
    A0 = *reinterpret_cast<f16x8*>(&z0_); \
    A1 = *reinterpret_cast<f16x8*>(&z1_); }

#define MFMA_F16(A, B, C) __builtin_amdgcn_mfma_f32_16x16x32_f16( \
    A, *reinterpret_cast<f16x8*>(&(B)), C, 0, 0, 0)

// one conv phase (27 taps): gathers + B from LDS; R13/R16 barrier schedule.
#define RUN_PHASE(DEF, WGBLP) { \
    const unsigned char* wgbl_ = (WGBLP); \
    asm volatile("s_waitcnt lgkmcnt(0)" ::: "memory"); \
    __builtin_amdgcn_s_barrier(); \
    STAGE_SLAB(0); \
    WSTAGE(wgbl_, 0); \
    float2 oc0, oc1, on0, on1; \
    oc0 = make_float2(0.f, 0.f); oc1 = oc0; on0 = oc0; on1 = oc0; \
    if (DEF) { oc0 = READ_OFF(0, 0); oc1 = READ_OFF(1, 0); } \
    asm volatile("s_waitcnt vmcnt(0)" ::: "memory"); \
    __builtin_amdgcn_s_barrier(); \
    __builtin_amdgcn_sched_barrier(0); \
    _Pragma("unroll 1") \
    for (int kt = 0; kt < 3; ++kt) { \
        if (kt > 0) { \
            asm volatile("s_waitcnt lgkmcnt(0)" ::: "memory"); \
            __builtin_amdgcn_s_barrier(); \
            STAGE_SLAB(kt); \
            asm volatile("s_waitcnt vmcnt(0)" ::: "memory"); \
            __builtin_amdgcn_s_barrier(); \
            __builtin_amdgcn_sched_barrier(0); \
        } \
        _Pragma("unroll 1") \
        for (int k9 = 0; k9 < 9; ++k9) { \
            int k = kt * 9 + k9; \
            if (k > 0) { \
                asm volatile("s_waitcnt vmcnt(0) lgkmcnt(0)" ::: "memory"); \
                __builtin_amdgcn_s_barrier(); \
                __builtin_amdgcn_sched_barrier(0); \
            } \
            if (k + 1 < NTAPS) { \
                WSTAGE(wgbl_, k + 1); \
                if (DEF) { on0 = READ_OFF(0, k + 1); on1 = READ_OFF(1, k + 1); } \
            } \
            int kh = k9 / 3, kw = k9 - (k9 / 3) * 3; \
            f16x8 a00, a01, a10, a11; \
            if (DEF) { GATHER_D(0, oc0, a00, a01); GATHER_D(1, oc1, a10, a11); } \
            else     { GATHER_C(0, a00, a01);      GATHER_C(1, a10, a11); } \
            const unsigned char* br_ = smem + WBUF_OFF + ((k & 1) << 13) + lr * 128; \
            _Pragma("unroll") \
            for (int n = 0; n < 4; ++n) { \
                f16x8 b0_ = *(const f16x8*)(br_ + n * 2048 + s0); \
                f16x8 b1_ = *(const f16x8*)(br_ + n * 2048 + s1); \
                acc[0][n] = MFMA_F16(a00, b0_, acc[0][n]); \
                acc[0][n] = MFMA_F16(a01, b1_, acc[0][n]); \
                acc[1][n] = MFMA_F16(a10, b0_, acc[1][n]); \
                acc[1][n] = MFMA_F16(a11, b1_, acc[1][n]); \
            } \
            oc0 = on0; oc1 = on1; \
        } \
    } }

// ---------------------------------------------------------------------------
// dcn_zp: fused (offset conv + deformable conv); 256 threads, 4 waves x 32
// locs (2 rows each), full K per wave, B shared across the 2 row-tiles,
// zero-padded halo (checkless gathers).
//   EPI 1: +bias+leaky -> f16 [loc][64].  EPI 2: +bias+residual -> f32 NCDHW.
// ---------------------------------------------------------------------------
template<int EPI>
__global__ __launch_bounds__(256, 2)
void dcn_zp(const unsigned short* __restrict__ xin,   // f16 [L][64]
            const unsigned short* __restrict__ Wtoff, // f16 [27][64][64] swz
            const unsigned short* __restrict__ Wtm,   // f16 [27][64][64] swz
            const float* __restrict__ boff,           // [54]
            const float* __restrict__ bmain,          // [64]
            const float* __restrict__ resid,          // f32 NCDHW (EPI==2)
            const unsigned char* __restrict__ zb,     // 4KB zeros
            float* __restrict__ outf,
            unsigned short* __restrict__ outh)
{
    __shared__ __align__(16) unsigned char smem[SMEM_B];

    const int tid  = threadIdx.x;
    const int wv   = tid >> 6, lane = tid & 63;
    const int lr   = lane & 15, lk = lane >> 4;

    // XCD-contiguous swizzle: 504 = 8 x 63 (bijective)
    const int bid = blockIdx.x;
    const int wg  = (bid & 7) * 63 + (bid >> 3);
    const int t   = wg / 72;
    const int rg  = (wg % 72) / 6;
    const int cg  = wg % 6;
    const int row0 = rg * TR;
    const int col0 = cg * TC;

    const unsigned char* xb = (const unsigned char*)xin;

    // weight B-read slot offsets (2-way, free)
    const int s0 = ((lk + lr) & 7) << 4;
    const int s1 = ((lk + 4 + lr) & 7) << 4;

    f32x4 acc[2][4];
#pragma unroll
    for (int mt = 0; mt < 2; ++mt)
#pragma unroll
        for (int n = 0; n < 4; ++n) acc[mt][n] = (f32x4){0.f, 0.f, 0.f, 0.f};

    // ================ PHASE A: offset conv -> soff LDS ================
    RUN_PHASE(false, (const unsigned char*)Wtoff);

#pragma unroll
    for (int n = 0; n < 4; ++n) {
        int o = n * 16 + lr;
        if (o < 54) {
            float bvA = boff[o];
#pragma unroll
            for (int mt = 0; mt < 2; ++mt)
#pragma unroll
                for (int i = 0; i < 4; ++i) {
                    int l = (2 * wv + mt) * 16 + lk * 4 + i;   // block-local loc
                    float vv = acc[mt][n][i] + bvA;
                    *(unsigned short*)(smem + SOFF_OFF + l * SOFF_STRIDE + o * 2) =
                        __half_as_ushort(__float2half(vv));
                }
        }
    }
    __syncthreads();   // offsets ready

    // ================ PHASE B: deformable conv ================
#pragma unroll
    for (int mt = 0; mt < 2; ++mt)
#pragma unroll
        for (int n = 0; n < 4; ++n) acc[mt][n] = (f32x4){0.f, 0.f, 0.f, 0.f};

    RUN_PHASE(true, (const unsigned char*)Wtm);

    // ---- epilogue. C/D: col=lr (out ch within n*16), row=lk*4+i (loc col)
    float bv[4];
#pragma unroll
    for (int n = 0; n < 4; ++n) bv[n] = bmain[n * 16 + lr];

    if (EPI == 1) {
#pragma unroll
        for (int mt = 0; mt < 2; ++mt) {
            size_t lrowmt = (size_t)t * HW + (size_t)(row0 + 2 * wv + mt) * W_DIM + col0;
#pragma unroll
            for (int n = 0; n < 4; ++n)
#pragma unroll
                for (int i = 0; i < 4; ++i) {
                    int lc = lk * 4 + i;
                    float vv = acc[mt][n][i] + bv[n];
                    vv = (vv > 0.f) ? vv : 0.1f * vv;
                    outh[(lrowmt + lc) * 64 + n * 16 + lr] =
                        __half_as_ushort(__float2half(vv));
                }
        }
    } else {
        __syncthreads();   // halo dead; wave-private 8KB transpose regions
        float* tf = (float*)(smem + (wv << 13));
#pragma unroll
        for (int mt = 0; mt < 2; ++mt)
#pragma unroll
            for (int n = 0; n < 4; ++n)
#pragma unroll
                for (int i = 0; i < 4; ++i) {
                    int l = mt * 16 + lk * 4 + i;              // 0..31
                    int och = n * 16 + lr;
                    tf[l * 64 + ((och + 2 * l) & 63)] = acc[mt][n][i] + bv[n];
                }
        asm volatile("s_waitcnt lgkmcnt(0)" ::: "memory");
        __builtin_amdgcn_sched_barrier(0);
        int j = lane & 15, gq = lane >> 4;
#pragma unroll
        for (int mt = 0; mt < 2; ++mt) {
            size_t lrowmt = (size_t)t * HW + (size_t)(row0 + 2 * wv + mt) * W_DIM + col0;
#pragma unroll
            for (int it = 0; it < 16; ++it) {
                int och = gq * 16 + it;
                int l = mt * 16 + j;
                float val = tf[l * 64 + ((och + 2 * l) & 63)];
                size_t gi = (size_t)och * L_DIM + lrowmt + j;
                outf[gi] = val + resid[gi];
            }
        }
    }
}

// ---------------------------------------------------------------------------
extern "C" void kernel_launch(void* const* d_in, const int* in_sizes, int n_in,
                              void* d_out, int out_size, void* d_ws, size_t ws_size,
                              hipStream_t stream)
{
    const float* x     = (const float*)d_in[0];
    const float* woff0 = (const float*)d_in[1];
    const float* boff0 = (const float*)d_in[2];
    const float* w0    = (const float*)d_in[3];
    const float* b0    = (const float*)d_in[4];
    const float* woff1 = (const float*)d_in[5];
    const float* boff1 = (const float*)d_in[6];
    const float* w1    = (const float*)d_in[7];
    const float* b1    = (const float*)d_in[8];
    float* out = (float*)d_out;

    unsigned char* ws = (unsigned char*)d_ws;
    unsigned short* Wt  = (unsigned short*)ws;                  // 884736 B (4x f16 [27][64][64] swz)
    unsigned short* xt  = (unsigned short*)(ws + 884736);       // 8257536 B f16 [L][64]
    unsigned short* y   = (unsigned short*)(ws + 9142272);      // 8257536 B f16 [L][64]
    unsigned char*  zb  = ws + 17399808;                        // 4096 B zeros

    zfill<<<1, 256, 0, stream>>>((int4*)zb);
    prep_weights<<<1728, 256, 0, stream>>>(woff0, w0, woff1, w1, Wt);
    transpose_x<<<1008, 256, 0, stream>>>(x, (unsigned*)xt);

    const int grid = T_DIM * (H_DIM / TR) * (W_DIM / TC);   // 504 x 256 threads
    const int WSZ  = NTAPS * 64 * 64;                       // 110592

    // layer 0 (fused offset-conv + deform + leaky) : xt -> y
    dcn_zp<1><<<grid, 256, 0, stream>>>(xt, Wt,           Wt + WSZ,     boff0, b0, nullptr, zb, nullptr, y);
    // layer 1 (fused offset-conv + deform + residual) : y -> out
    dcn_zp<2><<<grid, 256, 0, stream>>>(y,  Wt + 2 * WSZ, Wt + 3 * WSZ, boff1, b1, x,       zb, out, nullptr);
}